// Round 2
// baseline (83.196 us; speedup 1.0000x reference)
//
#include <hip/hip_runtime.h>

// B=2048, L=128, V=30522, D=768. Masked-mean pooling over ragged prefixes.
#define BB 2048
#define LL 128
#define DD 768
#define NT 192          // 3 waves; each thread owns one float4 column
#define DV (DD / 4)     // 192 float4 per row
#define CHUNK 32        // tokens per partial-sum block
#define CH (LL / CHUNK) // 4 chunks per batch row

// ---------- kernel 1: per-chunk partial sums into ws[B][CH][DV] ----------
__global__ __launch_bounds__(NT) void partial_sum_kernel(
    const int* __restrict__ ids,      // [B, L]
    const int* __restrict__ mask,     // [B, L] 0/1 left-contiguous
    const float* __restrict__ emb,    // [V, D]
    float* __restrict__ ws)           // [B*CH, DV] float4
{
    const int bc = blockIdx.x;
    const int b  = bc >> 2;           // CH == 4
    const int c  = bc & 3;
    const int t  = threadIdx.x;

    __shared__ int s_ids[CHUNK];
    __shared__ int s_part[2];

    // count valid tokens for this row (mask is 0/1, left-contiguous)
    if (t < LL) {
        int m = mask[b * LL + t];
        unsigned long long bal = __ballot(m != 0);  // waves 0,1 fully in-branch
        if ((t & 63) == 0) s_part[t >> 6] = __popcll(bal);
    }
    __syncthreads();
    const int cnt = s_part[0] + s_part[1];

    const int l0 = c * CHUNK;
    const int n  = min(cnt, l0 + CHUNK) - l0;   // tokens in this chunk
    if (n <= 0) return;                          // block-uniform exit

    if (t < n) s_ids[t] = ids[b * LL + l0 + t];
    __syncthreads();

    const float4* __restrict__ embv = reinterpret_cast<const float4*>(emb);

    float ax = 0.f, ay = 0.f, az = 0.f, aw = 0.f;
    int l = 0;
    for (; l + 8 <= n; l += 8) {
        float4 r0 = embv[s_ids[l + 0] * DV + t];
        float4 r1 = embv[s_ids[l + 1] * DV + t];
        float4 r2 = embv[s_ids[l + 2] * DV + t];
        float4 r3 = embv[s_ids[l + 3] * DV + t];
        float4 r4 = embv[s_ids[l + 4] * DV + t];
        float4 r5 = embv[s_ids[l + 5] * DV + t];
        float4 r6 = embv[s_ids[l + 6] * DV + t];
        float4 r7 = embv[s_ids[l + 7] * DV + t];
        ax += r0.x + r1.x + r2.x + r3.x + r4.x + r5.x + r6.x + r7.x;
        ay += r0.y + r1.y + r2.y + r3.y + r4.y + r5.y + r6.y + r7.y;
        az += r0.z + r1.z + r2.z + r3.z + r4.z + r5.z + r6.z + r7.z;
        aw += r0.w + r1.w + r2.w + r3.w + r4.w + r5.w + r6.w + r7.w;
    }
    for (; l < n; ++l) {
        float4 r = embv[s_ids[l] * DV + t];
        ax += r.x; ay += r.y; az += r.z; aw += r.w;
    }

    float4 o; o.x = ax; o.y = ay; o.z = az; o.w = aw;
    reinterpret_cast<float4*>(ws)[bc * DV + t] = o;
}

// ---------- kernel 2: reduce <=CH partials, divide by count ----------
__global__ __launch_bounds__(NT) void finalize_kernel(
    const int* __restrict__ mask,
    const float* __restrict__ ws,
    float* __restrict__ out)
{
    const int b = blockIdx.x;
    const int t = threadIdx.x;

    __shared__ int s_part[2];
    if (t < LL) {
        int m = mask[b * LL + t];
        unsigned long long bal = __ballot(m != 0);
        if ((t & 63) == 0) s_part[t >> 6] = __popcll(bal);
    }
    __syncthreads();
    const int cnt = s_part[0] + s_part[1];         // >= 1
    const int nch = (cnt + CHUNK - 1) >> 5;        // active chunks, >= 1

    const float4* __restrict__ wsv = reinterpret_cast<const float4*>(ws);
    float4 a = wsv[(b * CH + 0) * DV + t];
    for (int c = 1; c < nch; ++c) {
        float4 p = wsv[(b * CH + c) * DV + t];
        a.x += p.x; a.y += p.y; a.z += p.z; a.w += p.w;
    }
    const float inv = 1.0f / (float)cnt;
    a.x *= inv; a.y *= inv; a.z *= inv; a.w *= inv;
    reinterpret_cast<float4*>(out)[b * DV + t] = a;
}

// ---------- fallback (R0 kernel): one block per row ----------
__global__ __launch_bounds__(NT) void masked_mean_pool_kernel(
    const int* __restrict__ ids,
    const int* __restrict__ mask,
    const float* __restrict__ emb,
    float* __restrict__ out)
{
    const int b = blockIdx.x;
    const int t = threadIdx.x;

    __shared__ int s_ids[LL];
    __shared__ int s_part[2];

    if (t < LL) {
        s_ids[t] = ids[b * LL + t];
        int m = mask[b * LL + t];
        unsigned long long bal = __ballot(m != 0);
        if ((t & 63) == 0) s_part[t >> 6] = __popcll(bal);
    }
    __syncthreads();
    const int cnt = s_part[0] + s_part[1];

    const float4* __restrict__ embv = reinterpret_cast<const float4*>(emb);
    float ax = 0.f, ay = 0.f, az = 0.f, aw = 0.f;
    int l = 0;
    for (; l + 8 <= cnt; l += 8) {
        float4 r0 = embv[s_ids[l + 0] * DV + t];
        float4 r1 = embv[s_ids[l + 1] * DV + t];
        float4 r2 = embv[s_ids[l + 2] * DV + t];
        float4 r3 = embv[s_ids[l + 3] * DV + t];
        float4 r4 = embv[s_ids[l + 4] * DV + t];
        float4 r5 = embv[s_ids[l + 5] * DV + t];
        float4 r6 = embv[s_ids[l + 6] * DV + t];
        float4 r7 = embv[s_ids[l + 7] * DV + t];
        ax += r0.x + r1.x + r2.x + r3.x + r4.x + r5.x + r6.x + r7.x;
        ay += r0.y + r1.y + r2.y + r3.y + r4.y + r5.y + r6.y + r7.y;
        az += r0.z + r1.z + r2.z + r3.z + r4.z + r5.z + r6.z + r7.z;
        aw += r0.w + r1.w + r2.w + r3.w + r4.w + r5.w + r6.w + r7.w;
    }
    for (; l < cnt; ++l) {
        float4 r = embv[s_ids[l] * DV + t];
        ax += r.x; ay += r.y; az += r.z; aw += r.w;
    }
    const float inv = 1.0f / (float)cnt;
    float4 o;
    o.x = ax * inv; o.y = ay * inv; o.z = az * inv; o.w = aw * inv;
    reinterpret_cast<float4*>(out)[b * DV + t] = o;
}

extern "C" void kernel_launch(void* const* d_in, const int* in_sizes, int n_in,
                              void* d_out, int out_size, void* d_ws, size_t ws_size,
                              hipStream_t stream) {
    const int*   ids  = (const int*)d_in[0];
    const int*   mask = (const int*)d_in[1];
    const float* emb  = (const float*)d_in[2];
    float*       out  = (float*)d_out;

    const size_t ws_needed = (size_t)BB * CH * DD * sizeof(float);  // 25.2 MB
    if (ws_size >= ws_needed) {
        float* ws = (float*)d_ws;
        partial_sum_kernel<<<BB * CH, NT, 0, stream>>>(ids, mask, emb, ws);
        finalize_kernel<<<BB, NT, 0, stream>>>(mask, ws, out);
    } else {
        masked_mean_pool_kernel<<<BB, NT, 0, stream>>>(ids, mask, emb, out);
    }
}

// Round 3
// 65.562 us; speedup vs baseline: 1.2690x; 1.2690x over previous
//
#include <hip/hip_runtime.h>

// B=2048, L=128, V=30522, D=768. Masked-mean pooling over ragged prefixes.
// One block per batch row; thread t owns float4 column t of D=768.
// 8 independent accumulators -> 8 concurrent global_load_dwordx4 per thread
// (the R2 profile showed VGPR_Count=28: the ordered-sum version serialized
// the gathers to ~2 in flight; this is the MLP fix).
#define BB 2048
#define LL 128
#define DD 768
#define NT 192
#define DV (DD / 4)

__device__ __forceinline__ void f4acc(float4& a, const float4 v) {
    a.x += v.x; a.y += v.y; a.z += v.z; a.w += v.w;
}

__global__ __launch_bounds__(NT, 4) void masked_mean_pool_kernel(
    const int* __restrict__ ids,      // [B, L] int32
    const int* __restrict__ mask,     // [B, L] int32 (0/1, left-contiguous)
    const float* __restrict__ emb,    // [V, D] fp32
    float* __restrict__ out)          // [B, D] fp32
{
    const int b = blockIdx.x;
    const int t = threadIdx.x;

    __shared__ int s_ids[LL];
    __shared__ int s_part[2];

    if (t < LL) {
        s_ids[t] = ids[b * LL + t];
        int m = mask[b * LL + t];
        unsigned long long bal = __ballot(m != 0);
        if ((t & 63) == 0) s_part[t >> 6] = __popcll(bal);
    }
    __syncthreads();
    const int cnt = s_part[0] + s_part[1];   // >= 1

    const float4* __restrict__ embv = reinterpret_cast<const float4*>(emb);

    float4 a0 = {0,0,0,0}, a1 = {0,0,0,0}, a2 = {0,0,0,0}, a3 = {0,0,0,0};
    float4 a4 = {0,0,0,0}, a5 = {0,0,0,0}, a6 = {0,0,0,0}, a7 = {0,0,0,0};

    int l = 0;
    for (; l + 8 <= cnt; l += 8) {
        // 8 fully independent load->accumulate chains; compiler can keep
        // all 8 dwordx4 gathers outstanding.
        const int i0 = s_ids[l + 0], i1 = s_ids[l + 1];
        const int i2 = s_ids[l + 2], i3 = s_ids[l + 3];
        const int i4 = s_ids[l + 4], i5 = s_ids[l + 5];
        const int i6 = s_ids[l + 6], i7 = s_ids[l + 7];
        f4acc(a0, embv[i0 * DV + t]);
        f4acc(a1, embv[i1 * DV + t]);
        f4acc(a2, embv[i2 * DV + t]);
        f4acc(a3, embv[i3 * DV + t]);
        f4acc(a4, embv[i4 * DV + t]);
        f4acc(a5, embv[i5 * DV + t]);
        f4acc(a6, embv[i6 * DV + t]);
        f4acc(a7, embv[i7 * DV + t]);
    }
    for (; l < cnt; ++l) {
        f4acc(a0, embv[s_ids[l] * DV + t]);
    }

    // Pairwise combine (fixed order), then scale.
    f4acc(a0, a4); f4acc(a1, a5); f4acc(a2, a6); f4acc(a3, a7);
    f4acc(a0, a2); f4acc(a1, a3);
    f4acc(a0, a1);

    const float inv = 1.0f / (float)cnt;
    float4 o;
    o.x = a0.x * inv; o.y = a0.y * inv; o.z = a0.z * inv; o.w = a0.w * inv;
    reinterpret_cast<float4*>(out)[b * DV + t] = o;
}

extern "C" void kernel_launch(void* const* d_in, const int* in_sizes, int n_in,
                              void* d_out, int out_size, void* d_ws, size_t ws_size,
                              hipStream_t stream) {
    const int*   ids  = (const int*)d_in[0];
    const int*   mask = (const int*)d_in[1];
    const float* emb  = (const float*)d_in[2];
    float*       out  = (float*)d_out;

    masked_mean_pool_kernel<<<BB, NT, 0, stream>>>(ids, mask, emb, out);
}

// Round 4
// 63.450 us; speedup vs baseline: 1.3112x; 1.0333x over previous
//
#include <hip/hip_runtime.h>

// B=2048, L=128, V=30522, D=768. Masked-mean pooling over ragged prefixes.
// One block per row; thread t owns float4 column t (192*16B = one 3KB row per
// token). Loop-carried software pipeline of depth 8: r0..r7 hold the previous
// 8 tokens' data while the next 8 gathers are issued into the same names.
// All 8 quads are live across the iteration boundary, so the compiler MUST
// keep 8 distinct dest quads -> ~8 dwordx4 gathers in flight per wave.
// (R3's load-feeds-add-in-same-statement version collapsed to 1 dest quad,
// VGPR_Count=36 -> MLP never actually tested.)
#define BB 2048
#define LL 128
#define DD 768
#define NT 192
#define DV (DD / 4)

__device__ __forceinline__ void f4acc(float4& a, const float4 v) {
    a.x += v.x; a.y += v.y; a.z += v.z; a.w += v.w;
}

__global__ __launch_bounds__(NT, 6) void masked_mean_pool_kernel(
    const int* __restrict__ ids,      // [B, L] int32
    const int* __restrict__ mask,     // [B, L] int32 (0/1, left-contiguous)
    const float* __restrict__ emb,    // [V, D] fp32
    float* __restrict__ out)          // [B, D] fp32
{
    const int b = blockIdx.x;
    const int t = threadIdx.x;

    __shared__ int s_ids[LL];
    __shared__ int s_part[2];

    if (t < LL) {
        s_ids[t] = ids[b * LL + t];
        int m = mask[b * LL + t];
        unsigned long long bal = __ballot(m != 0);
        if ((t & 63) == 0) s_part[t >> 6] = __popcll(bal);
    }
    __syncthreads();
    const int cnt = s_part[0] + s_part[1];   // >= 1

    const float4* __restrict__ embv = reinterpret_cast<const float4*>(emb);

    float4 a0 = {0,0,0,0}, a1 = {0,0,0,0}, a2 = {0,0,0,0}, a3 = {0,0,0,0};

    int l = 0;
    if (cnt >= 8) {
        // prologue: fill the 8-deep pipeline
        float4 r0 = embv[s_ids[0] * DV + t];
        float4 r1 = embv[s_ids[1] * DV + t];
        float4 r2 = embv[s_ids[2] * DV + t];
        float4 r3 = embv[s_ids[3] * DV + t];
        float4 r4 = embv[s_ids[4] * DV + t];
        float4 r5 = embv[s_ids[5] * DV + t];
        float4 r6 = embv[s_ids[6] * DV + t];
        float4 r7 = embv[s_ids[7] * DV + t];

        for (l = 8; l + 8 <= cnt; l += 8) {
            const int i0 = s_ids[l + 0], i1 = s_ids[l + 1];
            const int i2 = s_ids[l + 2], i3 = s_ids[l + 3];
            const int i4 = s_ids[l + 4], i5 = s_ids[l + 5];
            const int i6 = s_ids[l + 6], i7 = s_ids[l + 7];
            // retire previous group, immediately re-issue into same regs
            f4acc(a0, r0); r0 = embv[i0 * DV + t];
            f4acc(a1, r1); r1 = embv[i1 * DV + t];
            f4acc(a2, r2); r2 = embv[i2 * DV + t];
            f4acc(a3, r3); r3 = embv[i3 * DV + t];
            f4acc(a0, r4); r4 = embv[i4 * DV + t];
            f4acc(a1, r5); r5 = embv[i5 * DV + t];
            f4acc(a2, r6); r6 = embv[i6 * DV + t];
            f4acc(a3, r7); r7 = embv[i7 * DV + t];
        }
        // drain
        f4acc(a0, r0); f4acc(a1, r1); f4acc(a2, r2); f4acc(a3, r3);
        f4acc(a0, r4); f4acc(a1, r5); f4acc(a2, r6); f4acc(a3, r7);
    }
    // remainder (and cnt < 8 case)
    for (; l < cnt; ++l) {
        f4acc(a0, embv[s_ids[l] * DV + t]);
    }

    // fixed-order combine, then scale
    f4acc(a0, a2); f4acc(a1, a3);
    f4acc(a0, a1);

    const float inv = 1.0f / (float)cnt;
    float4 o;
    o.x = a0.x * inv; o.y = a0.y * inv; o.z = a0.z * inv; o.w = a0.w * inv;
    reinterpret_cast<float4*>(out)[b * DV + t] = o;
}

extern "C" void kernel_launch(void* const* d_in, const int* in_sizes, int n_in,
                              void* d_out, int out_size, void* d_ws, size_t ws_size,
                              hipStream_t stream) {
    const int*   ids  = (const int*)d_in[0];
    const int*   mask = (const int*)d_in[1];
    const float* emb  = (const float*)d_in[2];
    float*       out  = (float*)d_out;

    masked_mean_pool_kernel<<<BB, NT, 0, stream>>>(ids, mask, emb, out);
}